// Round 12
// baseline (1019.852 us; speedup 1.0000x reference)
//
#include <hip/hip_runtime.h>

typedef __attribute__((ext_vector_type(8))) short short8;
typedef __attribute__((ext_vector_type(4))) float floatx4;
typedef __attribute__((ext_vector_type(4))) float fx4;
typedef __attribute__((ext_vector_type(4))) unsigned ux4;
typedef __attribute__((ext_vector_type(2))) unsigned ux2;

#define B_DIM 64
#define L_SEQ 2048
#define D_H   64
#define BQ    16
#define QK_SCALE 0.1803368801111137f   // log2(e)/8 : folded into Q in prepass

// ---- main-kernel LDS layout (bytes) ----
#define E_BYTES   (BQ * L_SEQ * 2)          // 65536: P/e [16][2048] bf16, swizzled
#define CB_OFF    E_BYTES                   // 8192: combine buffer [2][16][64] f32
#define RS_OFF    (CB_OFF + 8192)           // 512: rsum [8][16] f32
#define RI_OFF    (RS_OFF + 512)            // 64: rinv [16] f32
#define LDS_TOTAL (RI_OFF + 64)             // 74304 -> 2 blocks/CU

#if defined(__has_builtin)
#  if __has_builtin(__builtin_amdgcn_exp2f)
#    define EXP2(x) __builtin_amdgcn_exp2f(x)
#  else
#    define EXP2(x) exp2f(x)
#  endif
#else
#  define EXP2(x) exp2f(x)
#endif

__device__ __forceinline__ short f2bf(float f) {
    unsigned u = __builtin_bit_cast(unsigned, f);
    u += 0x7FFFu + ((u >> 16) & 1u);
    return (short)(u >> 16);
}
__device__ __forceinline__ float bf2f_lo(unsigned w) {
    return __builtin_bit_cast(float, w << 16);
}
__device__ __forceinline__ float bf2f_hi(unsigned w) {
    return __builtin_bit_cast(float, w & 0xFFFF0000u);
}
__device__ __forceinline__ unsigned pk2bf(float a, float b) {
    unsigned ua = __builtin_bit_cast(unsigned, a);
    unsigned ub = __builtin_bit_cast(unsigned, b);
    ua += 0x7FFFu + ((ua >> 16) & 1u);
    ub += 0x7FFFu + ((ub >> 16) & 1u);
    return (ua >> 16) | (ub & 0xFFFF0000u);
}
// 16B-slot XOR swizzle ([16][2048] bf16, row stride 4096 B)
__device__ __forceinline__ int sidx(int row, int colbyte) {
    return row * 4096 + (colbyte ^ ((row & 7) << 4));
}

// ================= prepass 1: Q (pre-scaled) and K -> bf16 =================
__global__ __launch_bounds__(256) void prep_qk(const float* __restrict__ q,
                                               const float* __restrict__ k,
                                               unsigned short* __restrict__ qb,
                                               unsigned short* __restrict__ kb) {
    size_t i = (size_t)blockIdx.x * 256 + threadIdx.x;     // x4 elements
    fx4 q4 = __builtin_nontemporal_load((const fx4*)q + i);
    fx4 k4 = __builtin_nontemporal_load((const fx4*)k + i);
    ux2 qo, ko;
    qo[0] = pk2bf(q4[0] * QK_SCALE, q4[1] * QK_SCALE);
    qo[1] = pk2bf(q4[2] * QK_SCALE, q4[3] * QK_SCALE);
    ko[0] = pk2bf(k4[0], k4[1]);
    ko[1] = pk2bf(k4[2], k4[3]);
    *((ux2*)qb + i) = qo;
    *((ux2*)kb + i) = ko;
}

// ================= prepass 2: V -> bf16 transposed [B][D][L] =================
__global__ __launch_bounds__(256) void prep_vt(const float* __restrict__ v,
                                               unsigned short* __restrict__ vt) {
    __shared__ float tile[64][65];
    const int b  = blockIdx.x >> 5;
    const int kc = (blockIdx.x & 31) * 64;
    const int t  = threadIdx.x;
    {
        const int r = t >> 2, c4 = (t & 3) * 16;
        const float* src = v + ((size_t)b * L_SEQ + kc + r) * D_H + c4;
        #pragma unroll
        for (int j = 0; j < 4; ++j) {
            fx4 f = __builtin_nontemporal_load((const fx4*)(src + j * 4));
            tile[r][c4 + j * 4 + 0] = f[0]; tile[r][c4 + j * 4 + 1] = f[1];
            tile[r][c4 + j * 4 + 2] = f[2]; tile[r][c4 + j * 4 + 3] = f[3];
        }
    }
    __syncthreads();
    const int d = t >> 2, kq = (t & 3) * 16;
    ux4 o0, o1;
    o0[0] = pk2bf(tile[kq + 0][d], tile[kq + 1][d]);
    o0[1] = pk2bf(tile[kq + 2][d], tile[kq + 3][d]);
    o0[2] = pk2bf(tile[kq + 4][d], tile[kq + 5][d]);
    o0[3] = pk2bf(tile[kq + 6][d], tile[kq + 7][d]);
    o1[0] = pk2bf(tile[kq + 8][d], tile[kq + 9][d]);
    o1[1] = pk2bf(tile[kq +10][d], tile[kq +11][d]);
    o1[2] = pk2bf(tile[kq +12][d], tile[kq +13][d]);
    o1[3] = pk2bf(tile[kq +14][d], tile[kq +15][d]);
    unsigned short* dst = vt + ((size_t)b * D_H + d) * L_SEQ + kc + kq;
    *(ux4*)dst = o0;
    *(ux4*)(dst + 8) = o1;
}

// ================= main kernel: fused QK+softmax (swapped operands) =================
// Wave w owns k-section [w*256, w*256+256). Lane (l16,l4): q = l16, per tile t
// holds S[q=l16][k = w*256 + t*16 + 4*l4 + r] (R9-verified D-mapping).
// 2 barriers total; attn stores overlap PV.
__global__ __launch_bounds__(512, 4)
void sdpa_main(const void* __restrict__ mask,
               const unsigned short* __restrict__ qb,
               const unsigned short* __restrict__ kbuf,
               const unsigned short* __restrict__ vt,
               float* __restrict__ out, float* __restrict__ attn)
{
    __shared__ char lds[LDS_TOTAL];
    float* rsum   = (float*)(lds + RS_OFF);
    float* s_rinv = (float*)(lds + RI_OFF);

    const int tid  = threadIdx.x;
    const int wave = tid >> 6;
    const int lane = tid & 63;
    const int l16  = lane & 15;
    const int l4   = lane >> 4;

    const int bid  = blockIdx.x;                 // 8192, %8==0 -> bijective XCD swizzle
    const int sbid = (bid & 7) * 1024 + (bid >> 3);
    const int b     = sbid >> 7;
    const int qbase = (sbid & 127) * BQ;

    // ---------- mask element-size detection (uniform) ----------
    const unsigned* mwords = (const unsigned*)mask;
    bool wordMode = true;
    #pragma unroll 8
    for (int i = 0; i < 64; ++i) {
        unsigned w = mwords[i];
        if (!(w == 0u || w == 1u || w == 0x3F800000u)) wordMode = false;
    }

    const size_t qrow_g = (size_t)b * L_SEQ + qbase + l16;   // this lane's q row
    const size_t mrow   = qrow_g * (size_t)L_SEQ;
    const int    kS     = wave * 256;

    // ---------- byte-mode mask prefetch: 16 dwords, issued before any MFMA ----------
    unsigned mk[16];
    if (!wordMode) {
        #pragma unroll
        for (int t = 0; t < 16; ++t)
            mk[t] = *(const unsigned*)((const unsigned char*)mask + mrow + kS + t * 16 + 4 * l4);
    }

    // ---------- Q fragment (B-operand): B[col=q=l16][d=l4*8..] ----------
    const unsigned short* qrow = qb + qrow_g * D_H + l4 * 8;
    const short8 aq0 = *(const short8*)(qrow);
    const short8 aq1 = *(const short8*)(qrow + 32);

    const unsigned short* kbb = kbuf + (size_t)b * L_SEQ * D_H;

    // ---------- fused pass: QK^T -> mask -> exp2 -> psum, pack -> regs + LDS ----------
    ux2 ev[16];                                  // 4 bf16 per tile, static-indexed
    float psum = 0.f;
    short8 kc0, kc1;
    {
        const unsigned short* kr = kbb + (size_t)(kS + l16) * D_H + l4 * 8;
        kc0 = *(const short8*)kr;
        kc1 = *(const short8*)(kr + 32);
    }
    #pragma unroll
    for (int t = 0; t < 16; ++t) {
        short8 kn0, kn1;
        if (t < 15) {                            // depth-1 lookahead, named regs
            const unsigned short* kr = kbb + (size_t)(kS + (t + 1) * 16 + l16) * D_H + l4 * 8;
            kn0 = *(const short8*)kr;
            kn1 = *(const short8*)(kr + 32);
        } else { kn0 = kc0; kn1 = kc1; }

        floatx4 s = {0.f, 0.f, 0.f, 0.f};
        s = __builtin_amdgcn_mfma_f32_16x16x32_bf16(kc0, aq0, s, 0, 0, 0);
        s = __builtin_amdgcn_mfma_f32_16x16x32_bf16(kc1, aq1, s, 0, 0, 0);

        unsigned md;
        if (!wordMode) {
            md = mk[t];
        } else {
            const unsigned* mw = mwords + mrow + kS + t * 16 + 4 * l4;
            ux4 w0 = *(const ux4*)mw;
            md = (w0[0] ? 0xFFu : 0u) | (w0[1] ? 0xFF00u : 0u) |
                 (w0[2] ? 0xFF0000u : 0u) | (w0[3] ? 0xFF000000u : 0u);
        }
        float e0 = (md & 0x000000FFu) ? 0.f : EXP2(s[0]);
        float e1 = (md & 0x0000FF00u) ? 0.f : EXP2(s[1]);
        float e2 = (md & 0x00FF0000u) ? 0.f : EXP2(s[2]);
        float e3 = (md & 0xFF000000u) ? 0.f : EXP2(s[3]);
        psum += (e0 + e1) + (e2 + e3);
        ux2 ew;
        ew[0] = pk2bf(e0, e1);
        ew[1] = pk2bf(e2, e3);
        ev[t] = ew;
        // e -> LDS, k-consecutive 8B: byte col = 2*(kS + t*16 + 4*l4)
        *(ux2*)(lds + sidx(l16, wave * 512 + t * 32 + l4 * 8)) = ew;
        kc0 = kn0; kc1 = kn1;
    }

    // ---------- section row-sum across the 4 l4-lanes of this q-row ----------
    psum += __shfl_xor(psum, 16, 64);
    psum += __shfl_xor(psum, 32, 64);
    if (l4 == 0) rsum[wave * 16 + l16] = psum;

    __syncthreads();                             // barrier 1: e-LDS + rsum ready

    float rs = 0.f;
    #pragma unroll
    for (int w = 0; w < 8; ++w) rs += rsum[w * 16 + l16];
    const float ri = 1.0f / rs;
    if (wave == 0 && l4 == 0) s_rinv[l16] = ri;  // for the out epilogue (ordered by barrier 2)

    // ---------- vt prefetch (in flight under the attn stores) ----------
    const int dg = wave & 3;
    const int kh = wave >> 2;
    const unsigned short* vtb = vt + ((size_t)b * D_H + dg * 16 + l16) * L_SEQ + kh * 32 + l4 * 8;
    short8 vb0 = *(const short8*)(vtb);
    short8 vb1 = *(const short8*)(vtb + 64);
    short8 vb2 = *(const short8*)(vtb + 128);
    short8 vb3 = *(const short8*)(vtb + 192);

    // ---------- attn stores (fire-and-forget; drained only at barrier 2, after PV) ----------
    {
        float* arow = attn + mrow;
        #pragma unroll
        for (int t = 0; t < 16; ++t) {
            fx4 o;
            o[0] = bf2f_lo(ev[t][0]) * ri; o[1] = bf2f_hi(ev[t][0]) * ri;
            o[2] = bf2f_lo(ev[t][1]) * ri; o[3] = bf2f_hi(ev[t][1]) * ri;
            *(fx4*)(arow + kS + t * 16 + 4 * l4) = o;
        }
    }

    // ---------- PV: O = P·V (R7-verified, depth-4 vt pipeline) ----------
    floatx4 oacc = {0.f, 0.f, 0.f, 0.f};
    for (int cc = 0; cc < 8; ++cc) {
        short8 vn0, vn1, vn2, vn3;
        if (cc < 7) {
            const unsigned short* vp = vtb + (cc + 1) * 256;
            vn0 = *(const short8*)(vp);
            vn1 = *(const short8*)(vp + 64);
            vn2 = *(const short8*)(vp + 128);
            vn3 = *(const short8*)(vp + 192);
        } else { vn0 = vb0; vn1 = vb1; vn2 = vb2; vn3 = vb3; }
        const int kbase2 = cc * 512 + kh * 64 + l4 * 16;
        short8 pf0 = *(short8*)(lds + sidx(l16, kbase2));
        oacc = __builtin_amdgcn_mfma_f32_16x16x32_bf16(pf0, vb0, oacc, 0, 0, 0);
        short8 pf1 = *(short8*)(lds + sidx(l16, kbase2 + 128));
        oacc = __builtin_amdgcn_mfma_f32_16x16x32_bf16(pf1, vb1, oacc, 0, 0, 0);
        short8 pf2 = *(short8*)(lds + sidx(l16, kbase2 + 256));
        oacc = __builtin_amdgcn_mfma_f32_16x16x32_bf16(pf2, vb2, oacc, 0, 0, 0);
        short8 pf3 = *(short8*)(lds + sidx(l16, kbase2 + 384));
        oacc = __builtin_amdgcn_mfma_f32_16x16x32_bf16(pf3, vb3, oacc, 0, 0, 0);
        vb0 = vn0; vb1 = vn1; vb2 = vn2; vb3 = vn3;
    }

    // ---------- combine k-halves ----------
    float* s_comb = (float*)(lds + CB_OFF);
    #pragma unroll
    for (int r = 0; r < 4; ++r)
        s_comb[kh * 1024 + (l4 * 4 + r) * 64 + dg * 16 + l16] = oacc[r];
    __syncthreads();                             // barrier 2: comb ready (+ store drain, covered by PV)
    if (tid < 256) {
        const int qo = tid >> 4, dc = tid & 15;
        float4 a = *(float4*)(s_comb + qo * 64 + dc * 4);
        float4 c = *(float4*)(s_comb + 1024 + qo * 64 + dc * 4);
        const float rio = s_rinv[qo];
        fx4 o;
        o[0] = (a.x + c.x) * rio; o[1] = (a.y + c.y) * rio;
        o[2] = (a.z + c.z) * rio; o[3] = (a.w + c.w) * rio;
        *(fx4*)(out + ((size_t)b * L_SEQ + qbase + qo) * D_H + dc * 4) = o;
    }
}

// ================= fallback (no workspace): round-7 monolithic kernel =================
#define FB_SC_BYTES  (16 * L_SEQ * 2)
#define FB_CB_OFF    FB_SC_BYTES
#define FB_RI_OFF    (FB_CB_OFF + 8192)
#define FB_LDS_TOTAL (FB_RI_OFF + 64)

__global__ __launch_bounds__(512, 4)
void sdpa_fb(const float* __restrict__ qf, const float* __restrict__ kf,
             const float* __restrict__ vf32, const void* __restrict__ mask,
             float* __restrict__ out, float* __restrict__ attn)
{
    extern __shared__ char lds[];
    float* s_rinv = (float*)(lds + FB_RI_OFF);

    const int tid  = threadIdx.x;
    const int wave = tid >> 6;
    const int lane = tid & 63;
    const int l16  = lane & 15;
    const int l4   = lane >> 4;

    const int bid  = blockIdx.x;
    const int sbid = (bid & 7) * 1024 + (bid >> 3);
    const int b     = sbid >> 7;
    const int qbase = (sbid & 127) * 16;

    const unsigned* mwords = (const unsigned*)mask;
    bool wordMode = true;
    #pragma unroll 8
    for (int i = 0; i < 64; ++i) {
        unsigned w = mwords[i];
        if (!(w == 0u || w == 1u || w == 0x3F800000u)) wordMode = false;
    }

    const int qa = tid >> 5;
    const int ca = tid & 31;
    const size_t rowbase = ((size_t)b * L_SEQ + qbase + qa) * (size_t)L_SEQ;

    ux2 mm[8];
    if (!wordMode) {
        #pragma unroll
        for (int j = 0; j < 8; ++j)
            mm[j] = __builtin_nontemporal_load(
                (const ux2*)((const unsigned char*)mask + rowbase + ca * 8 + j * 256));
    }

    short8 aq0, aq1;
    {
        const float* qrow = qf + ((size_t)b * L_SEQ + qbase + l16) * D_H + l4 * 8;
        #pragma unroll
        for (int h = 0; h < 2; ++h) {
            float4 f0 = *(const float4*)(qrow + h * 32);
            float4 f1 = *(const float4*)(qrow + h * 32 + 4);
            short8 a;
            a[0] = f2bf(f0.x * QK_SCALE); a[1] = f2bf(f0.y * QK_SCALE);
            a[2] = f2bf(f0.z * QK_SCALE); a[3] = f2bf(f0.w * QK_SCALE);
            a[4] = f2bf(f1.x * QK_SCALE); a[5] = f2bf(f1.y * QK_SCALE);
            a[6] = f2bf(f1.z * QK_SCALE); a[7] = f2bf(f1.w * QK_SCALE);
            if (h == 0) aq0 = a; else aq1 = a;
        }
    }
    #pragma unroll 2
    for (int t = 0; t < 16; ++t) {
        const int kt = wave * 16 + t;
        const float* krow = kf + ((size_t)b * L_SEQ + kt * 16 + l16) * D_H + l4 * 8;
        floatx4 c = {0.f, 0.f, 0.f, 0.f};
        #pragma unroll
        for (int h = 0; h < 2; ++h) {
            float4 f0 = *(const float4*)(krow + h * 32);
            float4 f1 = *(const float4*)(krow + h * 32 + 4);
            short8 bk;
            bk[0] = f2bf(f0.x); bk[1] = f2bf(f0.y); bk[2] = f2bf(f0.z); bk[3] = f2bf(f0.w);
            bk[4] = f2bf(f1.x); bk[5] = f2bf(f1.y); bk[6] = f2bf(f1.z); bk[7] = f2bf(f1.w);
            c = __builtin_amdgcn_mfma_f32_16x16x32_bf16(h ? aq1 : aq0, bk, c, 0, 0, 0);
        }
        #pragma unroll
        for (int r = 0; r < 4; ++r)
            *(short*)(lds + sidx(l4 * 4 + r, (kt * 16 + l16) * 2)) = f2bf(c[r]);
    }
    __syncthreads();

    ux4 ev[8];
    float psum = 0.f;
    #pragma unroll 2
    for (int j = 0; j < 8; ++j) {
        const int col = ca * 8 + j * 256;
        ux4 sw = *(ux4*)(lds + sidx(qa, col * 2));
        unsigned mbits;
        if (!wordMode) {
            unsigned lo = mm[j][0], hi = mm[j][1];
            mbits = ((lo & 0x000000FFu) ? 1u : 0u) | ((lo & 0x0000FF00u) ? 2u : 0u) |
                    ((lo & 0x00FF0000u) ? 4u : 0u) | ((lo & 0xFF000000u) ? 8u : 0u) |
                    ((hi & 0x000000FFu) ? 16u : 0u) | ((hi & 0x0000FF00u) ? 32u : 0u) |
                    ((hi & 0x00FF0000u) ? 64u : 0u) | ((hi & 0xFF000000u) ? 128u : 0u);
        } else {
            const unsigned* mp = mwords + rowbase + col;
            ux4 ma = __builtin_nontemporal_load((const ux4*)mp);
            ux4 mb = __builtin_nontemporal_load((const ux4*)mp + 1);
            mbits = (ma[0] ? 1u : 0u) | (ma[1] ? 2u : 0u) | (ma[2] ? 4u : 0u) | (ma[3] ? 8u : 0u) |
                    (mb[0] ? 16u : 0u) | (mb[1] ? 32u : 0u) | (mb[2] ? 64u : 0u) | (mb[3] ? 128u : 0u);
        }
        float e0 = EXP2(bf2f_lo(sw[0])), e1 = EXP2(bf2f_hi(sw[0]));
        float e2 = EXP2(bf2f_lo(sw[1])), e3 = EXP2(bf2f_hi(sw[1]));
        float e4 = EXP2(bf2f_lo(sw[2])), e5 = EXP2(bf2f_hi(sw[2]));
        float e6 = EXP2(bf2f_lo(sw[3])), e7 = EXP2(bf2f_hi(sw[3]));
        e0 = (mbits & 1u)   ? 0.f : e0;  e1 = (mbits & 2u)   ? 0.f : e1;
        e2 = (mbits & 4u)   ? 0.f : e2;  e3 = (mbits & 8u)   ? 0.f : e3;
        e4 = (mbits & 16u)  ? 0.f : e4;  e5 = (mbits & 32u)  ? 0.f : e5;
        e6 = (mbits & 64u)  ? 0.f : e6;  e7 = (mbits & 128u) ? 0.f : e7;
        psum += ((e0 + e1) + (e2 + e3)) + ((e4 + e5) + (e6 + e7));
        ev[j][0] = pk2bf(e0, e1); ev[j][1] = pk2bf(e2, e3);
        ev[j][2] = pk2bf(e4, e5); ev[j][3] = pk2bf(e6, e7);
        *(ux4*)(lds + sidx(qa, col * 2)) = ev[j];
    }
    #pragma unroll
    for (int off = 1; off < 32; off <<= 1) psum += __shfl_xor(psum, off, 64);
    const float ri = 1.0f / psum;
    if (ca == 0) s_rinv[qa] = ri;

    {
        float* arow = attn + rowbase;
        #pragma unroll 2
        for (int j = 0; j < 8; ++j) {
            const int col = ca * 8 + j * 256;
            fx4 o0, o1;
            o0[0] = bf2f_lo(ev[j][0]) * ri; o0[1] = bf2f_hi(ev[j][0]) * ri;
            o0[2] = bf2f_lo(ev[j][1]) * ri; o0[3] = bf2f_hi(ev[j][1]) * ri;
            o1[0] = bf2f_lo(ev[j][2]) * ri; o1[1] = bf2f_hi(ev[j][2]) * ri;
            o1[2] = bf2f_lo(ev[j][3]) * ri; o1[3] = bf2f_hi(ev[j][3]) * ri;
            *(fx4*)(arow + col)     = o0;
            *(fx4*)(arow + col + 4) = o1;
        }
    }
    __syncthreads();

    const int dg = wave & 3;
    const int kh = wave >> 2;
    floatx4 oacc = {0.f, 0.f, 0.f, 0.f};
    const float* vp0 = vf32 + ((size_t)b * L_SEQ + kh * 32 + l4 * 8) * D_H + dg * 16 + l16;
    for (int ch = 0; ch < 32; ++ch) {
        const float* vp = vp0 + (size_t)ch * 64 * D_H;
        short8 vfr;
        #pragma unroll
        for (int i = 0; i < 8; ++i) vfr[i] = f2bf(vp[i * D_H]);
        short8 pf = *(short8*)(lds + sidx(l16, ch * 128 + kh * 64 + l4 * 16));
        oacc = __builtin_amdgcn_mfma_f32_16x16x32_bf16(pf, vfr, oacc, 0, 0, 0);
    }

    float* s_comb = (float*)(lds + FB_CB_OFF);
    #pragma unroll
    for (int r = 0; r < 4; ++r)
        s_comb[kh * 1024 + (l4 * 4 + r) * 64 + dg * 16 + l16] = oacc[r];
    __syncthreads();
    if (tid < 256) {
        const int qo = tid >> 4, dc = tid & 15;
        float4 a = *(float4*)(s_comb + qo * 64 + dc * 4);
        float4 c = *(float4*)(s_comb + 1024 + qo * 64 + dc * 4);
        const float rio = s_rinv[qo];
        fx4 o;
        o[0] = (a.x + c.x) * rio; o[1] = (a.y + c.y) * rio;
        o[2] = (a.z + c.z) * rio; o[3] = (a.w + c.w) * rio;
        *(fx4*)(out + ((size_t)b * L_SEQ + qbase + qo) * D_H + dc * 4) = o;
    }
}

extern "C" void kernel_launch(void* const* d_in, const int* in_sizes, int n_in,
                              void* d_out, int out_size, void* d_ws, size_t ws_size,
                              hipStream_t stream) {
    const float* q = (const float*)d_in[0];
    const float* k = (const float*)d_in[1];
    const float* v = (const float*)d_in[2];
    const void* mask = d_in[3];
    float* out  = (float*)d_out;
    float* attn = out + (size_t)B_DIM * L_SEQ * D_H;

    const size_t NE = (size_t)B_DIM * L_SEQ * D_H;          // 8,388,608
    dim3 grid(B_DIM * (L_SEQ / BQ), 1, 1);                  // 8192
    dim3 block(512, 1, 1);

    if (ws_size >= NE * 2 * 3) {
        unsigned short* qb = (unsigned short*)d_ws;
        unsigned short* kb = qb + NE;
        unsigned short* vt = kb + NE;
        hipLaunchKernelGGL(prep_qk, dim3(8192), dim3(256), 0, stream, q, k, qb, kb);
        hipLaunchKernelGGL(prep_vt, dim3(2048), dim3(256), 0, stream, v, vt);
        hipLaunchKernelGGL(sdpa_main, grid, block, 0, stream,
                           mask, qb, kb, vt, out, attn);
    } else {
        hipLaunchKernelGGL(sdpa_fb, grid, block, FB_LDS_TOTAL, stream,
                           q, k, v, mask, out, attn);
    }
}

// Round 13
// 823.536 us; speedup vs baseline: 1.2384x; 1.2384x over previous
//
#include <hip/hip_runtime.h>

typedef __attribute__((ext_vector_type(8))) short short8;
typedef __attribute__((ext_vector_type(4))) float floatx4;
typedef __attribute__((ext_vector_type(4))) float fx4;
typedef __attribute__((ext_vector_type(4))) unsigned ux4;
typedef __attribute__((ext_vector_type(2))) unsigned ux2;

#define B_DIM 64
#define L_SEQ 2048
#define D_H   64
#define BQ    16
#define QK_SCALE 0.1803368801111137f   // log2(e)/8 : folded into Q in prepass

// ---- main-kernel LDS layout (bytes) ----
#define SC_BYTES  (BQ * L_SEQ * 2)          // 65536: scores/P [16][2048] bf16, swizzled
#define CB_OFF    SC_BYTES                  // 8192: combine buffer [2][16][64] f32
#define RI_OFF    (CB_OFF + 8192)           // 64: row inv [16] f32
#define LDS_TOTAL (RI_OFF + 64)             // 73792 -> 2 blocks/CU

#if defined(__has_builtin)
#  if __has_builtin(__builtin_amdgcn_exp2f)
#    define EXP2(x) __builtin_amdgcn_exp2f(x)
#  else
#    define EXP2(x) exp2f(x)
#  endif
#else
#  define EXP2(x) exp2f(x)
#endif

// Light barrier: order LDS only (lgkmcnt), leave global stores in flight.
// __syncthreads would emit s_waitcnt vmcnt(0) and drain the attn store burst.
#define BARRIER_LDS()                                          \
    do {                                                       \
        asm volatile("s_waitcnt lgkmcnt(0)" ::: "memory");     \
        __builtin_amdgcn_sched_barrier(0);                     \
        __builtin_amdgcn_s_barrier();                          \
        __builtin_amdgcn_sched_barrier(0);                     \
    } while (0)

__device__ __forceinline__ short f2bf(float f) {
    unsigned u = __builtin_bit_cast(unsigned, f);
    u += 0x7FFFu + ((u >> 16) & 1u);
    return (short)(u >> 16);
}
__device__ __forceinline__ float bf2f_lo(unsigned w) {
    return __builtin_bit_cast(float, w << 16);
}
__device__ __forceinline__ float bf2f_hi(unsigned w) {
    return __builtin_bit_cast(float, w & 0xFFFF0000u);
}
__device__ __forceinline__ unsigned pk2bf(float a, float b) {
    unsigned ua = __builtin_bit_cast(unsigned, a);
    unsigned ub = __builtin_bit_cast(unsigned, b);
    ua += 0x7FFFu + ((ua >> 16) & 1u);
    ub += 0x7FFFu + ((ub >> 16) & 1u);
    return (ua >> 16) | (ub & 0xFFFF0000u);
}
// 16B-slot XOR swizzle
__device__ __forceinline__ int sidx(int row, int colbyte) {
    return row * 4096 + (colbyte ^ ((row & 7) << 4));
}

// ================= prepass 1: Q (pre-scaled) and K -> bf16 =================
__global__ __launch_bounds__(256) void prep_qk(const float* __restrict__ q,
                                               const float* __restrict__ k,
                                               unsigned short* __restrict__ qb,
                                               unsigned short* __restrict__ kb) {
    size_t i = (size_t)blockIdx.x * 256 + threadIdx.x;     // x4 elements
    fx4 q4 = __builtin_nontemporal_load((const fx4*)q + i);
    fx4 k4 = __builtin_nontemporal_load((const fx4*)k + i);
    ux2 qo, ko;
    qo[0] = pk2bf(q4[0] * QK_SCALE, q4[1] * QK_SCALE);
    qo[1] = pk2bf(q4[2] * QK_SCALE, q4[3] * QK_SCALE);
    ko[0] = pk2bf(k4[0], k4[1]);
    ko[1] = pk2bf(k4[2], k4[3]);
    *((ux2*)qb + i) = qo;
    *((ux2*)kb + i) = ko;
}

// ================= prepass 2: V -> bf16 transposed [B][D][L] =================
__global__ __launch_bounds__(256) void prep_vt(const float* __restrict__ v,
                                               unsigned short* __restrict__ vt) {
    __shared__ float tile[64][65];
    const int b  = blockIdx.x >> 5;
    const int kc = (blockIdx.x & 31) * 64;
    const int t  = threadIdx.x;
    {
        const int r = t >> 2, c4 = (t & 3) * 16;
        const float* src = v + ((size_t)b * L_SEQ + kc + r) * D_H + c4;
        #pragma unroll
        for (int j = 0; j < 4; ++j) {
            fx4 f = __builtin_nontemporal_load((const fx4*)(src + j * 4));
            tile[r][c4 + j * 4 + 0] = f[0]; tile[r][c4 + j * 4 + 1] = f[1];
            tile[r][c4 + j * 4 + 2] = f[2]; tile[r][c4 + j * 4 + 3] = f[3];
        }
    }
    __syncthreads();
    const int d = t >> 2, kq = (t & 3) * 16;
    ux4 o0, o1;
    o0[0] = pk2bf(tile[kq + 0][d], tile[kq + 1][d]);
    o0[1] = pk2bf(tile[kq + 2][d], tile[kq + 3][d]);
    o0[2] = pk2bf(tile[kq + 4][d], tile[kq + 5][d]);
    o0[3] = pk2bf(tile[kq + 6][d], tile[kq + 7][d]);
    o1[0] = pk2bf(tile[kq + 8][d], tile[kq + 9][d]);
    o1[1] = pk2bf(tile[kq +10][d], tile[kq +11][d]);
    o1[2] = pk2bf(tile[kq +12][d], tile[kq +13][d]);
    o1[3] = pk2bf(tile[kq +14][d], tile[kq +15][d]);
    unsigned short* dst = vt + ((size_t)b * D_H + d) * L_SEQ + kc + kq;
    *(ux4*)dst = o0;
    *(ux4*)(dst + 8) = o1;
}

#define LOADK(kt, r0, r1)                                                        \
    {                                                                            \
        const unsigned short* kr_ = kbb + (size_t)((kt) * 16 + l16) * D_H + l4 * 8; \
        r0 = *(const short8*)kr_;                                                \
        r1 = *(const short8*)(kr_ + 32);                                         \
    }

// ================= main kernel =================
template <bool PRE>
__global__ __launch_bounds__(512, 4)
void sdpa_kernel(const float* __restrict__ qf, const float* __restrict__ kf,
                 const float* __restrict__ vf32, const void* __restrict__ mask,
                 const unsigned short* __restrict__ qb,
                 const unsigned short* __restrict__ kb,
                 const unsigned short* __restrict__ vt,
                 float* __restrict__ out, float* __restrict__ attn)
{
    extern __shared__ char lds[];
    float* s_rinv = (float*)(lds + RI_OFF);

    const int tid  = threadIdx.x;
    const int wave = tid >> 6;
    const int lane = tid & 63;
    const int l16  = lane & 15;
    const int l4   = lane >> 4;

    const int bid  = blockIdx.x;                 // 8192, %8==0 -> bijective
    const int sbid = (bid & 7) * 1024 + (bid >> 3);
    const int b     = sbid >> 7;
    const int qbase = (sbid & 127) * BQ;

    // PV roles (needed early for the vt prefetch)
    const int dg = wave & 3;
    const int kh = wave >> 2;

    // ---------- mask element-size detection (uniform) ----------
    const unsigned* mwords = (const unsigned*)mask;
    bool wordMode = true;
    #pragma unroll 8
    for (int i = 0; i < 64; ++i) {
        unsigned w = mwords[i];
        if (!(w == 0u || w == 1u || w == 0x3F800000u)) wordMode = false;
    }

    const int qa = tid >> 5;                     // row for phase 2a
    const int ca = tid & 31;                     // 32 threads/row
    const size_t rowbase = ((size_t)b * L_SEQ + qbase + qa) * (size_t)L_SEQ;

    // ---------- byte-mode mask prefetch (hidden under phase 1) ----------
    ux2 mm[8];
    if (!wordMode) {
        #pragma unroll
        for (int j = 0; j < 8; ++j)
            mm[j] = __builtin_nontemporal_load(
                (const ux2*)((const unsigned char*)mask + rowbase + ca * 8 + j * 256));
    }

    // ---------- Phase 1: S = (QK^T)*log2e/8 -> swizzled LDS bf16 ----------
    short8 aq0, aq1;
    if constexpr (PRE) {
        const unsigned short* qrow = qb + ((size_t)b * L_SEQ + qbase + l16) * D_H + l4 * 8;
        aq0 = *(const short8*)(qrow);
        aq1 = *(const short8*)(qrow + 32);
    } else {
        const float* qrow = qf + ((size_t)b * L_SEQ + qbase + l16) * D_H + l4 * 8;
        #pragma unroll
        for (int h = 0; h < 2; ++h) {
            float4 f0 = *(const float4*)(qrow + h * 32);
            float4 f1 = *(const float4*)(qrow + h * 32 + 4);
            short8 a;
            a[0] = f2bf(f0.x * QK_SCALE); a[1] = f2bf(f0.y * QK_SCALE);
            a[2] = f2bf(f0.z * QK_SCALE); a[3] = f2bf(f0.w * QK_SCALE);
            a[4] = f2bf(f1.x * QK_SCALE); a[5] = f2bf(f1.y * QK_SCALE);
            a[6] = f2bf(f1.z * QK_SCALE); a[7] = f2bf(f1.w * QK_SCALE);
            if (h == 0) aq0 = a; else aq1 = a;
        }
    }
    if constexpr (PRE) {
        const unsigned short* kbb = kb + (size_t)b * L_SEQ * D_H;
        short8 c0a, c0b, c1a, c1b;
        LOADK(wave * 16 + 0, c0a, c0b);
        LOADK(wave * 16 + 1, c1a, c1b);
        #pragma unroll
        for (int g = 0; g < 8; ++g) {
            short8 n0a, n0b, n1a, n1b;
            if (g < 7) {
                LOADK(wave * 16 + 2 * g + 2, n0a, n0b);
                LOADK(wave * 16 + 2 * g + 3, n1a, n1b);
            } else {
                n0a = c0a; n0b = c0b; n1a = c1a; n1b = c1b;
            }
            const int kt0 = wave * 16 + 2 * g;
            floatx4 s0 = {0.f, 0.f, 0.f, 0.f};
            floatx4 s1 = {0.f, 0.f, 0.f, 0.f};
            s0 = __builtin_amdgcn_mfma_f32_16x16x32_bf16(aq0, c0a, s0, 0, 0, 0);
            s0 = __builtin_amdgcn_mfma_f32_16x16x32_bf16(aq1, c0b, s0, 0, 0, 0);
            s1 = __builtin_amdgcn_mfma_f32_16x16x32_bf16(aq0, c1a, s1, 0, 0, 0);
            s1 = __builtin_amdgcn_mfma_f32_16x16x32_bf16(aq1, c1b, s1, 0, 0, 0);
            #pragma unroll
            for (int r = 0; r < 4; ++r) {
                *(short*)(lds + sidx(l4 * 4 + r, (kt0 * 16 + l16) * 2))       = f2bf(s0[r]);
                *(short*)(lds + sidx(l4 * 4 + r, ((kt0 + 1) * 16 + l16) * 2)) = f2bf(s1[r]);
            }
            c0a = n0a; c0b = n0b; c1a = n1a; c1b = n1b;
        }
    } else {
        #pragma unroll 2
        for (int t = 0; t < 16; ++t) {
            const int kt = wave * 16 + t;
            const float* krow = kf + ((size_t)b * L_SEQ + kt * 16 + l16) * D_H + l4 * 8;
            floatx4 c = {0.f, 0.f, 0.f, 0.f};
            #pragma unroll
            for (int h = 0; h < 2; ++h) {
                float4 f0 = *(const float4*)(krow + h * 32);
                float4 f1 = *(const float4*)(krow + h * 32 + 4);
                short8 bk;
                bk[0] = f2bf(f0.x); bk[1] = f2bf(f0.y); bk[2] = f2bf(f0.z); bk[3] = f2bf(f0.w);
                bk[4] = f2bf(f1.x); bk[5] = f2bf(f1.y); bk[6] = f2bf(f1.z); bk[7] = f2bf(f1.w);
                c = __builtin_amdgcn_mfma_f32_16x16x32_bf16(h ? aq1 : aq0, bk, c, 0, 0, 0);
            }
            #pragma unroll
            for (int r = 0; r < 4; ++r)
                *(short*)(lds + sidx(l4 * 4 + r, (kt * 16 + l16) * 2)) = f2bf(c[r]);
        }
    }
    BARRIER_LDS();                               // barrier 1: scores ready (K loads may stay in flight)

    // ---------- vt prefetch: in flight under P2a's VALU work + attn stores ----------
    const unsigned short* vtb = nullptr;
    short8 vb0 = {}, vb1 = {}, vb2 = {}, vb3 = {};
    if constexpr (PRE) {
        vtb = vt + ((size_t)b * D_H + dg * 16 + l16) * L_SEQ + kh * 32 + l4 * 8;
        vb0 = *(const short8*)(vtb);
        vb1 = *(const short8*)(vtb + 64);
        vb2 = *(const short8*)(vtb + 128);
        vb3 = *(const short8*)(vtb + 192);
    }

    // ---------- Phase 2a: e = mask ? 0 : exp2(s); f32 row sums; pack bf16 ----------
    ux4 ev[8];
    float psum = 0.f;
    #pragma unroll 2
    for (int j = 0; j < 8; ++j) {
        const int col = ca * 8 + j * 256;
        ux4 sw = *(ux4*)(lds + sidx(qa, col * 2));
        unsigned mbits;
        if (!wordMode) {
            unsigned lo = mm[j][0], hi = mm[j][1];
            mbits = ((lo & 0x000000FFu) ? 1u : 0u) | ((lo & 0x0000FF00u) ? 2u : 0u) |
                    ((lo & 0x00FF0000u) ? 4u : 0u) | ((lo & 0xFF000000u) ? 8u : 0u) |
                    ((hi & 0x000000FFu) ? 16u : 0u) | ((hi & 0x0000FF00u) ? 32u : 0u) |
                    ((hi & 0x00FF0000u) ? 64u : 0u) | ((hi & 0xFF000000u) ? 128u : 0u);
        } else {
            const unsigned* mp = mwords + rowbase + col;
            ux4 ma = __builtin_nontemporal_load((const ux4*)mp);
            ux4 mb2 = __builtin_nontemporal_load((const ux4*)mp + 1);
            mbits = (ma[0] ? 1u : 0u) | (ma[1] ? 2u : 0u) | (ma[2] ? 4u : 0u) | (ma[3] ? 8u : 0u) |
                    (mb2[0] ? 16u : 0u) | (mb2[1] ? 32u : 0u) | (mb2[2] ? 64u : 0u) | (mb2[3] ? 128u : 0u);
        }
        float e0 = EXP2(bf2f_lo(sw[0])), e1 = EXP2(bf2f_hi(sw[0]));
        float e2 = EXP2(bf2f_lo(sw[1])), e3 = EXP2(bf2f_hi(sw[1]));
        float e4 = EXP2(bf2f_lo(sw[2])), e5 = EXP2(bf2f_hi(sw[2]));
        float e6 = EXP2(bf2f_lo(sw[3])), e7 = EXP2(bf2f_hi(sw[3]));
        e0 = (mbits & 1u)   ? 0.f : e0;  e1 = (mbits & 2u)   ? 0.f : e1;
        e2 = (mbits & 4u)   ? 0.f : e2;  e3 = (mbits & 8u)   ? 0.f : e3;
        e4 = (mbits & 16u)  ? 0.f : e4;  e5 = (mbits & 32u)  ? 0.f : e5;
        e6 = (mbits & 64u)  ? 0.f : e6;  e7 = (mbits & 128u) ? 0.f : e7;
        psum += ((e0 + e1) + (e2 + e3)) + ((e4 + e5) + (e6 + e7));
        ev[j][0] = pk2bf(e0, e1); ev[j][1] = pk2bf(e2, e3);
        ev[j][2] = pk2bf(e4, e5); ev[j][3] = pk2bf(e6, e7);
        *(ux4*)(lds + sidx(qa, col * 2)) = ev[j];
    }
    // 32-lane butterfly: every lane ends with its row's full sum -> local ri
    #pragma unroll
    for (int off = 1; off < 32; off <<= 1) psum += __shfl_xor(psum, off, 64);
    const float ri = 1.0f / psum;
    if (ca == 0) s_rinv[qa] = ri;                // for the epilogue only

    // ---------- attn write (registers; stores left in flight across the light barrier) ----------
    {
        float* arow = attn + rowbase;
        #pragma unroll 2
        for (int j = 0; j < 8; ++j) {
            const int col = ca * 8 + j * 256;
            fx4 o0, o1;
            o0[0] = bf2f_lo(ev[j][0]) * ri; o0[1] = bf2f_hi(ev[j][0]) * ri;
            o0[2] = bf2f_lo(ev[j][1]) * ri; o0[3] = bf2f_hi(ev[j][1]) * ri;
            o1[0] = bf2f_lo(ev[j][2]) * ri; o1[1] = bf2f_hi(ev[j][2]) * ri;
            o1[2] = bf2f_lo(ev[j][3]) * ri; o1[3] = bf2f_hi(ev[j][3]) * ri;
            *(fx4*)(arow + col)     = o0;
            *(fx4*)(arow + col + 4) = o1;
        }
    }
    BARRIER_LDS();                               // barrier 2: e-LDS ordered; attn stores NOT drained

    // ---------- Phase 2b: O = P·V (depth-4 software pipeline; covers the store drain) ----------
    floatx4 oacc = {0.f, 0.f, 0.f, 0.f};

    if constexpr (PRE) {
        for (int cc = 0; cc < 8; ++cc) {
            short8 vn0, vn1, vn2, vn3;
            if (cc < 7) {                        // issue next group's loads first
                const unsigned short* vp = vtb + (cc + 1) * 256;
                vn0 = *(const short8*)(vp);
                vn1 = *(const short8*)(vp + 64);
                vn2 = *(const short8*)(vp + 128);
                vn3 = *(const short8*)(vp + 192);
            } else {
                vn0 = vb0; vn1 = vb1; vn2 = vb2; vn3 = vb3;
            }
            const int kbase2 = cc * 512 + kh * 64 + l4 * 16;
            short8 pf0 = *(short8*)(lds + sidx(l16, kbase2));
            oacc = __builtin_amdgcn_mfma_f32_16x16x32_bf16(pf0, vb0, oacc, 0, 0, 0);
            short8 pf1 = *(short8*)(lds + sidx(l16, kbase2 + 128));
            oacc = __builtin_amdgcn_mfma_f32_16x16x32_bf16(pf1, vb1, oacc, 0, 0, 0);
            short8 pf2 = *(short8*)(lds + sidx(l16, kbase2 + 256));
            oacc = __builtin_amdgcn_mfma_f32_16x16x32_bf16(pf2, vb2, oacc, 0, 0, 0);
            short8 pf3 = *(short8*)(lds + sidx(l16, kbase2 + 384));
            oacc = __builtin_amdgcn_mfma_f32_16x16x32_bf16(pf3, vb3, oacc, 0, 0, 0);
            vb0 = vn0; vb1 = vn1; vb2 = vn2; vb3 = vn3;
        }
    } else {
        const float* vp0 = vf32 + ((size_t)b * L_SEQ + kh * 32 + l4 * 8) * D_H + dg * 16 + l16;
        for (int ch = 0; ch < 32; ++ch) {
            const float* vp = vp0 + (size_t)ch * 64 * D_H;
            short8 vfr;
            #pragma unroll
            for (int i = 0; i < 8; ++i) vfr[i] = f2bf(vp[i * D_H]);
            short8 pf = *(short8*)(lds + sidx(l16, ch * 128 + kh * 64 + l4 * 16));
            oacc = __builtin_amdgcn_mfma_f32_16x16x32_bf16(pf, vfr, oacc, 0, 0, 0);
        }
    }

    // combine k-halves in separate buffer (scores untouched -> one barrier only)
    float* s_comb = (float*)(lds + CB_OFF);
    #pragma unroll
    for (int r = 0; r < 4; ++r)
        s_comb[kh * 1024 + (l4 * 4 + r) * 64 + dg * 16 + l16] = oacc[r];
    BARRIER_LDS();                               // barrier 3: combine ready; stores still draining
    if (tid < 256) {
        const int qo = tid >> 4, dc = tid & 15;
        float4 a = *(float4*)(s_comb + qo * 64 + dc * 4);
        float4 c = *(float4*)(s_comb + 1024 + qo * 64 + dc * 4);
        const float rio = s_rinv[qo];
        fx4 o;
        o[0] = (a.x + c.x) * rio; o[1] = (a.y + c.y) * rio;
        o[2] = (a.z + c.z) * rio; o[3] = (a.w + c.w) * rio;
        *(fx4*)(out + ((size_t)b * L_SEQ + qbase + qo) * D_H + dc * 4) = o;
    }
}

extern "C" void kernel_launch(void* const* d_in, const int* in_sizes, int n_in,
                              void* d_out, int out_size, void* d_ws, size_t ws_size,
                              hipStream_t stream) {
    const float* q = (const float*)d_in[0];
    const float* k = (const float*)d_in[1];
    const float* v = (const float*)d_in[2];
    const void* mask = d_in[3];
    float* out  = (float*)d_out;
    float* attn = out + (size_t)B_DIM * L_SEQ * D_H;

    const size_t NE = (size_t)B_DIM * L_SEQ * D_H;          // 8,388,608
    dim3 grid(B_DIM * (L_SEQ / BQ), 1, 1);                  // 8192
    dim3 block(512, 1, 1);

    if (ws_size >= NE * 2 * 3) {
        unsigned short* qb = (unsigned short*)d_ws;
        unsigned short* kb = qb + NE;
        unsigned short* vt = kb + NE;
        hipLaunchKernelGGL(prep_qk, dim3(8192), dim3(256), 0, stream, q, k, qb, kb);
        hipLaunchKernelGGL(prep_vt, dim3(2048), dim3(256), 0, stream, v, vt);
        hipLaunchKernelGGL((sdpa_kernel<true>), grid, block, LDS_TOTAL, stream,
                           q, k, v, mask, qb, kb, vt, out, attn);
    } else {
        hipLaunchKernelGGL((sdpa_kernel<false>), grid, block, LDS_TOTAL, stream,
                           q, k, v, mask, (const unsigned short*)nullptr,
                           (const unsigned short*)nullptr, (const unsigned short*)nullptr,
                           out, attn);
    }
}